// Round 8
// baseline (507.870 us; speedup 1.0000x reference)
//
#include <hip/hip_runtime.h>
#include <hip/hip_bf16.h>
#include <math.h>

#define NN 1024
#define AA 4096
#define CC 10000
#define NT 79
#define BM 128
#define BN 128

typedef __attribute__((ext_vector_type(8))) short short8;
typedef __attribute__((ext_vector_type(4))) float f32x4;

// ws layout (byte offsets, 256-aligned)
#define OFF_COUNT   0u          // int[C]        40960
#define OFF_HEAD    40960u      // int[C]        40960  (init 0xFF = -1)
#define OFF_NEXT    81920u      // int[N]        4096
#define OFF_T3H     86016u      // float[N]      4096
#define OFF_RAUG    90112u      // float[N]      4096
#define OFF_PART    94208u      // float[NT*N*2] 647168
#define OFF_FEATB   741376u     // bf16[N*A]     8388608
#define OFF_A1B     9129984u    // bf16[N*A]     8388608
#define OFF_A2B     17518592u   // bf16[N*A]     8388608
#define WS_BASE     25907200u
#define OFF_WB      25907200u   // bf16[C*A]     81920000
#define OFF_W2B     107827200u  // bf16[C*A]     81920000
#define WS_BIG      189747200u

__device__ inline unsigned short f2bf(float x) {
    union { float f; unsigned u; } v; v.f = x;
    unsigned r = v.u + 0x7FFFu + ((v.u >> 16) & 1u);
    return (unsigned short)(r >> 16);
}

__device__ __forceinline__ void gload16(const void* g, void* l) {
    __builtin_amdgcn_global_load_lds((const __attribute__((address_space(1))) void*)g,
                                     (__attribute__((address_space(3))) void*)l, 16, 0, 0);
}

__global__ void k_wconv(const float* __restrict__ fcw, unsigned short* __restrict__ wb,
                        unsigned short* __restrict__ w2b) {
    const size_t total = (size_t)CC * AA / 4;
    for (size_t i = (size_t)blockIdx.x * 256 + threadIdx.x; i < total; i += (size_t)gridDim.x * 256) {
        float4 v = ((const float4*)fcw)[i];
        ushort4 b, b2;
        b.x = f2bf(v.x); b.y = f2bf(v.y); b.z = f2bf(v.z); b.w = f2bf(v.w);
        b2.x = f2bf(v.x * v.x); b2.y = f2bf(v.y * v.y);
        b2.z = f2bf(v.z * v.z); b2.w = f2bf(v.w * v.w);
        ((ushort4*)wb)[i] = b;
        ((ushort4*)w2b)[i] = b2;
    }
}

// count + per-class linked list (head/next); replaces sumf/sumv atomics.
__global__ void k_count(const int* __restrict__ labels, int* count, int* head, int* nextp) {
    int n = blockIdx.x * 256 + threadIdx.x;
    if (n < NN) {
        int c = labels[n];
        atomicAdd(&count[c], 1);
        nextp[n] = atomicExch(&head[c], n);
    }
}

// Fused per-row prep: class stats via member-list walk -> cv -> bf16 A-operands.
__global__ void k_rowprep(const float* __restrict__ feat, const int* __restrict__ labels,
                          const float* __restrict__ fcw, const float* __restrict__ Ave,
                          const float* __restrict__ CoV, const float* __restrict__ Amount,
                          const int* __restrict__ ratio_p, const int* __restrict__ count,
                          const int* __restrict__ head, const int* __restrict__ nextp,
                          unsigned short* __restrict__ featb, unsigned short* __restrict__ a1b,
                          unsigned short* __restrict__ a2b, float* __restrict__ t3h) {
    int n = blockIdx.x;
    int tid = threadIdx.x;
    int c = labels[n];
    float cnt = (float)count[c];
    float inv = 1.0f / cnt;
    float amt = Amount[c];
    float w = cnt / (cnt + amt);
    float omw = 1.0f - w;
    float w1w = w * omw;
    float rf = (float)(*ratio_p);
    const int h = head[c];
    float t3 = 0.f;
    #pragma unroll 1
    for (int i = 0; i < 4; i++) {
        int i4 = i * 256 + tid;
        float sf[4] = {0.f, 0.f, 0.f, 0.f};
        float sq[4] = {0.f, 0.f, 0.f, 0.f};
        float fvv[4] = {0.f, 0.f, 0.f, 0.f};
        for (int m = h; m >= 0; m = nextp[m]) {
            float4 v = ((const float4*)(feat + (size_t)m * AA))[i4];
            sf[0] += v.x; sf[1] += v.y; sf[2] += v.z; sf[3] += v.w;
            sq[0] += v.x * v.x; sq[1] += v.y * v.y;
            sq[2] += v.z * v.z; sq[3] += v.w * v.w;
            if (m == n) { fvv[0] = v.x; fvv[1] = v.y; fvv[2] = v.z; fvv[3] = v.w; }
        }
        float4 cov = ((const float4*)(CoV + (size_t)c * AA))[i4];
        float4 avv = ((const float4*)(Ave + (size_t)c * AA))[i4];
        float4 wkv = ((const float4*)(fcw + (size_t)c * AA))[i4];
        float cva[4] = {cov.x, cov.y, cov.z, cov.w};
        float ava[4] = {avv.x, avv.y, avv.z, avv.w};
        float wka[4] = {wkv.x, wkv.y, wkv.z, wkv.w};
        ushort4 fb, a1, a2;
        unsigned short ob[12];
        #pragma unroll
        for (int j = 0; j < 4; j++) {
            float ave = sf[j] * inv;
            float var = sq[j] * inv - ave * ave;
            float d = ava[j] - ave;
            float cv = cva[j] * omw + var * w + w1w * d * d;
            float wk = wka[j];
            ob[j]     = f2bf(fvv[j]);
            ob[4 + j] = f2bf(0.5f * rf * cv);
            ob[8 + j] = f2bf(-rf * cv * wk);
            t3 += 0.5f * rf * cv * wk * wk;
        }
        fb.x = ob[0]; fb.y = ob[1]; fb.z = ob[2]; fb.w = ob[3];
        a1.x = ob[4]; a1.y = ob[5]; a1.z = ob[6]; a1.w = ob[7];
        a2.x = ob[8]; a2.y = ob[9]; a2.z = ob[10]; a2.w = ob[11];
        size_t o = (size_t)n * AA + (size_t)i4 * 4;
        *(ushort4*)(featb + o) = fb;
        *(ushort4*)(a1b + o) = a1;
        *(ushort4*)(a2b + o) = a2;
    }
    #pragma unroll
    for (int m = 32; m >= 1; m >>= 1) t3 += __shfl_xor(t3, m, 64);
    __shared__ float red[4];
    if ((tid & 63) == 0) red[tid >> 6] = t3;
    __syncthreads();
    if (tid == 0) t3h[n] = red[0] + red[1] + red[2] + red[3];
}

// ---------- fast GEMM: BK=32 double-buffer + COUNTED vmcnt pipeline (T4) ----
// Per wave, per K-step: 10 gload16 into buf^1 stay IN FLIGHT across the
// barrier (s_waitcnt vmcnt(10), never 0 mid-loop); they land under the next
// COMPUTE. Raw s_barrier (no compiler drain). Slot-XOR swizzle (round-6
// proven, 0 conflicts): LDS linear dest; involution on global source slot
// and on the COMPUTE read address.
__global__ __launch_bounds__(256, 2) void k_gemm(
    const unsigned short* __restrict__ featb, const unsigned short* __restrict__ a1b,
    const unsigned short* __restrict__ a2b, const unsigned short* __restrict__ wbp,
    const unsigned short* __restrict__ w2bp, const float* __restrict__ bias,
    const int* __restrict__ labels, const float* __restrict__ t3h,
    float* __restrict__ yout, float* __restrict__ rowaug, float* __restrict__ part) {
    __shared__ unsigned short sF[2][4096];
    __shared__ unsigned short sA1[2][4096];
    __shared__ unsigned short sA2[2][4096];
    __shared__ unsigned short sW[2][4096];
    __shared__ unsigned short sW2[2][4096];

    const int tid = threadIdx.x;
    const int lane = tid & 63;
    const int wid = tid >> 6;
    const int wr = wid >> 1, wc = wid & 1;
    const int lr = lane & 15, lk = lane >> 4;

    // XCD-chunked bijective swizzle: 632 = 8*79; nb-major per XCD.
    const int bid = blockIdx.x;
    const int wg = (bid & 7) * 79 + (bid >> 3);
    const int nb = wg >> 3;
    const int mb = wg & 7;
    const int brow = mb * BM, bcol = nb * BN;

    f32x4 accY[4][4], accS[4][4];
    f32x4 z = {0.f, 0.f, 0.f, 0.f};
    #pragma unroll
    for (int i = 0; i < 4; i++)
        #pragma unroll
        for (int j = 0; j < 4; j++) { accY[i][j] = z; accS[i][j] = z; }

    // staging geometry (BK=32): wave w stages rows [w*32,w*32+32): 2 issues
    // of 16 rows. lane l covers row +(l>>2); global slot = swizzled image of
    // the lane's linear LDS slot (involution per row-pair).
    const int lrow4 = lane >> 2;
    const int scolb = (((lane & 3) ^ ((lane >> 3) & 3)) * 16);
    const size_t R16 = (size_t)16 * AA * 2;
    const char* gF  = (const char*)featb + ((size_t)(brow + wid * 32 + lrow4) * AA) * 2 + scolb;
    const char* gA1 = (const char*)a1b  + ((size_t)(brow + wid * 32 + lrow4) * AA) * 2 + scolb;
    const char* gA2 = (const char*)a2b  + ((size_t)(brow + wid * 32 + lrow4) * AA) * 2 + scolb;
    int cls0 = bcol + wid * 32 + lrow4;      if (cls0 > CC - 1) cls0 = CC - 1;
    int cls1 = bcol + wid * 32 + 16 + lrow4; if (cls1 > CC - 1) cls1 = CC - 1;
    const char* gW0 = (const char*)wbp  + (size_t)cls0 * AA * 2 + scolb;
    const char* gW1 = (const char*)wbp  + (size_t)cls1 * AA * 2 + scolb;
    const char* gV0 = (const char*)w2bp + (size_t)cls0 * AA * 2 + scolb;
    const char* gV1 = (const char*)w2bp + (size_t)cls1 * AA * 2 + scolb;
    const int ldb = wid * 2048;              // byte offset: (wid*32)*64

#define STAGE(t, b) do {                                                     \
    const size_t ko_ = (size_t)(t) * 64;                                     \
    gload16(gF  + ko_,       (char*)&sF [b][0] + ldb);                       \
    gload16(gF  + R16 + ko_, (char*)&sF [b][0] + ldb + 1024);                \
    gload16(gA1 + ko_,       (char*)&sA1[b][0] + ldb);                       \
    gload16(gA1 + R16 + ko_, (char*)&sA1[b][0] + ldb + 1024);                \
    gload16(gA2 + ko_,       (char*)&sA2[b][0] + ldb);                       \
    gload16(gA2 + R16 + ko_, (char*)&sA2[b][0] + ldb + 1024);                \
    gload16(gW0 + ko_,       (char*)&sW [b][0] + ldb);                       \
    gload16(gW1 + ko_,       (char*)&sW [b][0] + ldb + 1024);                \
    gload16(gV0 + ko_,       (char*)&sW2[b][0] + ldb);                       \
    gload16(gV1 + ko_,       (char*)&sW2[b][0] + ldb + 1024);                \
} while (0)

#define COMPUTE(b) do {                                                      \
    short8 bw_[4], bw2_[4];                                                  \
    _Pragma("unroll")                                                        \
    for (int ni = 0; ni < 4; ni++) {                                         \
        int row = wc * 64 + ni * 16 + lr;                                    \
        int off = row * 64 + ((lk ^ ((row >> 1) & 3)) * 16);                 \
        bw_[ni]  = *(const short8*)((const char*)&sW [b][0] + off);          \
        bw2_[ni] = *(const short8*)((const char*)&sW2[b][0] + off);          \
    }                                                                        \
    _Pragma("unroll")                                                        \
    for (int mi = 0; mi < 4; mi++) {                                         \
        int row = wr * 64 + mi * 16 + lr;                                    \
        int off = row * 64 + ((lk ^ ((row >> 1) & 3)) * 16);                 \
        short8 af  = *(const short8*)((const char*)&sF [b][0] + off);        \
        short8 a1f = *(const short8*)((const char*)&sA1[b][0] + off);        \
        short8 a2f = *(const short8*)((const char*)&sA2[b][0] + off);        \
        _Pragma("unroll")                                                    \
        for (int ni = 0; ni < 4; ni++) {                                     \
            accY[mi][ni] = __builtin_amdgcn_mfma_f32_16x16x32_bf16(af,  bw_[ni],  accY[mi][ni], 0, 0, 0); \
            accS[mi][ni] = __builtin_amdgcn_mfma_f32_16x16x32_bf16(a1f, bw2_[ni], accS[mi][ni], 0, 0, 0); \
            accS[mi][ni] = __builtin_amdgcn_mfma_f32_16x16x32_bf16(a2f, bw_[ni],  accS[mi][ni], 0, 0, 0); \
        }                                                                    \
    }                                                                        \
} while (0)

    // prologue: fill both buffers; wait only for buf0 (vmcnt(10) leaves
    // buf1's 10 loads in flight).
    STAGE(0, 0);
    STAGE(1, 1);
    asm volatile("s_waitcnt vmcnt(10)" ::: "memory");
    __builtin_amdgcn_s_barrier();

    #pragma unroll 1
    for (int t = 0; t < 128; t += 2) {
        COMPUTE(0);
        asm volatile("s_waitcnt lgkmcnt(0)" ::: "memory");   // reads of buf0 done
        __builtin_amdgcn_s_barrier();                        // all waves done with buf0
        if (t + 2 < 128) {
            STAGE(t + 2, 0);                                 // overwrite buf0
            asm volatile("s_waitcnt vmcnt(10)" ::: "memory"); // buf1's loads landed
        } else {
            asm volatile("s_waitcnt vmcnt(0)" ::: "memory");
        }
        __builtin_amdgcn_s_barrier();                        // buf1 valid for all
        COMPUTE(1);
        asm volatile("s_waitcnt lgkmcnt(0)" ::: "memory");
        __builtin_amdgcn_s_barrier();
        if (t + 3 < 128) {
            STAGE(t + 3, 1);
            asm volatile("s_waitcnt vmcnt(10)" ::: "memory");
        } else {
            asm volatile("s_waitcnt vmcnt(0)" ::: "memory");
        }
        __builtin_amdgcn_s_barrier();
    }
#undef STAGE
#undef COMPUTE

    // ---- epilogue: y store + online (max,sumexp) partials + label extract ----
    float* sRed = (float*)&sF[0][0];
    #pragma unroll
    for (int mi = 0; mi < 4; mi++) {
        #pragma unroll
        for (int r = 0; r < 4; r++) {
            int rowt = wr * 64 + mi * 16 + lk * 4 + r;
            int grow = brow + rowt;
            int lab = labels[grow];
            float t3 = t3h[grow];
            float av[4];
            #pragma unroll
            for (int ni = 0; ni < 4; ni++) {
                int gcol = bcol + wc * 64 + ni * 16 + lr;
                float acy = accY[mi][ni][r];
                if (gcol < CC) {
                    float yy = acy + bias[gcol];
                    yout[(size_t)grow * CC + gcol] = yy;
                    float aug = yy + accS[mi][ni][r] + t3;
                    if (gcol == lab) rowaug[grow] = aug;
                    av[ni] = aug;
                } else {
                    av[ni] = -3.0e38f;
                }
            }
            float ml = fmaxf(fmaxf(av[0], av[1]), fmaxf(av[2], av[3]));
            #pragma unroll
            for (int m = 1; m < 16; m <<= 1) ml = fmaxf(ml, __shfl_xor(ml, m, 64));
            float sl = __expf(av[0] - ml) + __expf(av[1] - ml) +
                       __expf(av[2] - ml) + __expf(av[3] - ml);
            #pragma unroll
            for (int m = 1; m < 16; m <<= 1) sl += __shfl_xor(sl, m, 64);
            if (lr == 0) {
                sRed[rowt * 4 + wc * 2 + 0] = ml;
                sRed[rowt * 4 + wc * 2 + 1] = sl;
            }
        }
    }
    __syncthreads();
    if (tid < 128) {
        float m0 = sRed[tid * 4 + 0], s0 = sRed[tid * 4 + 1];
        float m1 = sRed[tid * 4 + 2], s1 = sRed[tid * 4 + 3];
        float M = fmaxf(m0, m1);
        float S = s0 * __expf(m0 - M) + s1 * __expf(m1 - M);
        size_t o = ((size_t)nb * NN + (brow + tid)) * 2;
        part[o] = M;
        part[o + 1] = S;
    }
}

// ---------- fallback GEMM (round-2 proven): in-kernel W conversion ----------
__global__ __launch_bounds__(256, 2) void k_gemm_fb(
    const unsigned short* __restrict__ featb, const unsigned short* __restrict__ a1b,
    const unsigned short* __restrict__ a2b, const float* __restrict__ fcw,
    const float* __restrict__ bias, const int* __restrict__ labels,
    const float* __restrict__ t3h, float* __restrict__ yout,
    float* __restrict__ rowaug, float* __restrict__ part) {
    __shared__ unsigned short sF[BM * 64];
    __shared__ unsigned short sA1[BM * 64];
    __shared__ unsigned short sA2[BM * 64];
    __shared__ unsigned short sW[BN * 64];
    __shared__ unsigned short sW2[BN * 64];

    const int tid = threadIdx.x;
    const int lane = tid & 63;
    const int wid = tid >> 6;
    const int wr = wid >> 1, wc = wid & 1;
    const int lr = lane & 15, lk = lane >> 4;
    const int nb = blockIdx.x, mb = blockIdx.y;
    const int brow = mb * BM, bcol = nb * BN;

    f32x4 accY[4][4], accS[4][4];
    f32x4 z = {0.f, 0.f, 0.f, 0.f};
    #pragma unroll
    for (int i = 0; i < 4; i++)
        #pragma unroll
        for (int j = 0; j < 4; j++) { accY[i][j] = z; accS[i][j] = z; }

    const int srow = tid >> 3;
    const int sblk = tid & 7;

    for (int kt = 0; kt < AA; kt += 64) {
        #pragma unroll
        for (int p = 0; p < 4; p++) {
            int row = p * 32 + srow;
            size_t g = (size_t)(brow + row) * AA + kt + sblk * 8;
            int pos = row * 128 + ((sblk * 16) ^ ((row & 7) << 4));
            *(uint4*)((char*)sF + pos)  = *(const uint4*)(featb + g);
            *(uint4*)((char*)sA1 + pos) = *(const uint4*)(a1b + g);
            *(uint4*)((char*)sA2 + pos) = *(const uint4*)(a2b + g);
        }
        #pragma unroll
        for (int p = 0; p < 8; p++) {
            int idx = p * 256 + tid;
            int wrow = idx >> 4;
            int col4 = idx & 15;
            int cls = bcol + wrow;
            float4 wv = {0.f, 0.f, 0.f, 0.f};
            if (cls < CC) wv = *(const float4*)(fcw + (size_t)cls * AA + kt + col4 * 4);
            ushort4 wb, w2b;
            wb.x = f2bf(wv.x); wb.y = f2bf(wv.y); wb.z = f2bf(wv.z); wb.w = f2bf(wv.w);
            w2b.x = f2bf(wv.x * wv.x); w2b.y = f2bf(wv.y * wv.y);
            w2b.z = f2bf(wv.z * wv.z); w2b.w = f2bf(wv.w * wv.w);
            int pos = wrow * 128 + ((col4 * 8) ^ ((wrow & 7) << 4));
            *(ushort4*)((char*)sW + pos) = wb;
            *(ushort4*)((char*)sW2 + pos) = w2b;
        }
        __syncthreads();
        #pragma unroll
        for (int k2 = 0; k2 < 2; k2++) {
            int kb = k2 * 64 + lk * 16;
            short8 bw[4], bw2[4];
            #pragma unroll
            for (int ni = 0; ni < 4; ni++) {
                int row = wc * 64 + ni * 16 + lr;
                int off = row * 128 + (kb ^ ((row & 7) << 4));
                bw[ni]  = *(const short8*)((const char*)sW + off);
                bw2[ni] = *(const short8*)((const char*)sW2 + off);
            }
            #pragma unroll
            for (int mi = 0; mi < 4; mi++) {
                int row = wr * 64 + mi * 16 + lr;
                int off = row * 128 + (kb ^ ((row & 7) << 4));
                short8 af  = *(const short8*)((const char*)sF + off);
                short8 a1f = *(const short8*)((const char*)sA1 + off);
                short8 a2f = *(const short8*)((const char*)sA2 + off);
                #pragma unroll
                for (int ni = 0; ni < 4; ni++) {
                    accY[mi][ni] = __builtin_amdgcn_mfma_f32_16x16x32_bf16(af,  bw[ni],  accY[mi][ni], 0, 0, 0);
                    accS[mi][ni] = __builtin_amdgcn_mfma_f32_16x16x32_bf16(a1f, bw2[ni], accS[mi][ni], 0, 0, 0);
                    accS[mi][ni] = __builtin_amdgcn_mfma_f32_16x16x32_bf16(a2f, bw[ni],  accS[mi][ni], 0, 0, 0);
                }
            }
        }
        __syncthreads();
    }

    float* sRed = (float*)sF;
    #pragma unroll
    for (int mi = 0; mi < 4; mi++) {
        #pragma unroll
        for (int r = 0; r < 4; r++) {
            int rowt = wr * 64 + mi * 16 + lk * 4 + r;
            int grow = brow + rowt;
            int lab = labels[grow];
            float t3 = t3h[grow];
            float av[4];
            #pragma unroll
            for (int ni = 0; ni < 4; ni++) {
                int gcol = bcol + wc * 64 + ni * 16 + lr;
                float acy = accY[mi][ni][r];
                if (gcol < CC) {
                    float yy = acy + bias[gcol];
                    yout[(size_t)grow * CC + gcol] = yy;
                    float aug = yy + accS[mi][ni][r] + t3;
                    if (gcol == lab) rowaug[grow] = aug;
                    av[ni] = aug;
                } else {
                    av[ni] = -3.0e38f;
                }
            }
            float ml = fmaxf(fmaxf(av[0], av[1]), fmaxf(av[2], av[3]));
            #pragma unroll
            for (int m = 1; m < 16; m <<= 1) ml = fmaxf(ml, __shfl_xor(ml, m, 64));
            float sl = __expf(av[0] - ml) + __expf(av[1] - ml) +
                       __expf(av[2] - ml) + __expf(av[3] - ml);
            #pragma unroll
            for (int m = 1; m < 16; m <<= 1) sl += __shfl_xor(sl, m, 64);
            if (lr == 0) {
                sRed[rowt * 4 + wc * 2 + 0] = ml;
                sRed[rowt * 4 + wc * 2 + 1] = sl;
            }
        }
    }
    __syncthreads();
    if (tid < 128) {
        float m0 = sRed[tid * 4 + 0], s0 = sRed[tid * 4 + 1];
        float m1 = sRed[tid * 4 + 2], s1 = sRed[tid * 4 + 3];
        float M = fmaxf(m0, m1);
        float S = s0 * __expf(m0 - M) + s1 * __expf(m1 - M);
        size_t o = ((size_t)nb * NN + (brow + tid)) * 2;
        part[o] = M;
        part[o + 1] = S;
    }
}

__global__ void k_loss(const float* __restrict__ part, const float* __restrict__ rowaug,
                       float* __restrict__ out0) {
    __shared__ float red[256];
    int n = blockIdx.x * 256 + threadIdx.x;
    float M = -3.0e38f;
    for (int t = 0; t < NT; t++) M = fmaxf(M, part[((size_t)t * NN + n) * 2]);
    float S = 0.f;
    for (int t = 0; t < NT; t++) {
        float m = part[((size_t)t * NN + n) * 2];
        float s = part[((size_t)t * NN + n) * 2 + 1];
        S += s * __expf(m - M);
    }
    float lse = M + logf(S);
    float rl = lse - rowaug[n];
    red[threadIdx.x] = rl;
    __syncthreads();
    for (int st = 128; st > 0; st >>= 1) {
        if (threadIdx.x < st) red[threadIdx.x] += red[threadIdx.x + st];
        __syncthreads();
    }
    if (threadIdx.x == 0) atomicAdd(out0, red[0] * (1.0f / (float)NN));
}

extern "C" void kernel_launch(void* const* d_in, const int* in_sizes, int n_in,
                              void* d_out, int out_size, void* d_ws, size_t ws_size,
                              hipStream_t stream) {
    const float* feat   = (const float*)d_in[0];
    const int*   labels = (const int*)d_in[1];
    const float* fcw    = (const float*)d_in[2];
    const float* bias   = (const float*)d_in[3];
    const float* Ave    = (const float*)d_in[4];
    const float* CoV    = (const float*)d_in[5];
    const float* Amount = (const float*)d_in[6];
    const int*   ratio  = (const int*)d_in[7];

    if (ws_size < WS_BASE) return;
    const bool big = ws_size >= WS_BIG;

    char* w = (char*)d_ws;
    int*   count  = (int*)(w + OFF_COUNT);
    int*   head   = (int*)(w + OFF_HEAD);
    int*   nextp  = (int*)(w + OFF_NEXT);
    float* t3h    = (float*)(w + OFF_T3H);
    float* rowaug = (float*)(w + OFF_RAUG);
    float* part   = (float*)(w + OFF_PART);
    unsigned short* featb = (unsigned short*)(w + OFF_FEATB);
    unsigned short* a1b   = (unsigned short*)(w + OFF_A1B);
    unsigned short* a2b   = (unsigned short*)(w + OFF_A2B);
    unsigned short* wb    = (unsigned short*)(w + OFF_WB);
    unsigned short* w2b   = (unsigned short*)(w + OFF_W2B);

    float* out = (float*)d_out;
    float* yout = out + 1;

    hipMemsetAsync(w + OFF_COUNT, 0, 40960, stream);
    hipMemsetAsync(w + OFF_HEAD, 0xFF, 40960, stream);   // head[c] = -1
    hipMemsetAsync(d_out, 0, 4, stream);                  // loss accumulator

    if (big) k_wconv<<<dim3(2048), dim3(256), 0, stream>>>(fcw, wb, w2b);
    k_count<<<dim3(4), dim3(256), 0, stream>>>(labels, count, head, nextp);
    k_rowprep<<<dim3(NN), dim3(256), 0, stream>>>(feat, labels, fcw, Ave, CoV, Amount,
                                                  ratio, count, head, nextp,
                                                  featb, a1b, a2b, t3h);
    if (big) {
        k_gemm<<<dim3(NT * 8), dim3(256), 0, stream>>>(featb, a1b, a2b, wb, w2b, bias,
                                                       labels, t3h, yout, rowaug, part);
    } else {
        k_gemm_fb<<<dim3(NT, 8), dim3(256), 0, stream>>>(featb, a1b, a2b, fcw, bias, labels,
                                                         t3h, yout, rowaug, part);
    }
    k_loss<<<dim3(4), dim3(256), 0, stream>>>(part, rowaug, out);
}

// Round 9
// 501.004 us; speedup vs baseline: 1.0137x; 1.0137x over previous
//
#include <hip/hip_runtime.h>
#include <hip/hip_bf16.h>
#include <math.h>

#define NN 1024
#define AA 4096
#define CC 10000
#define NT 79
#define BM 128
#define BN 128

typedef __attribute__((ext_vector_type(8))) short short8;
typedef __attribute__((ext_vector_type(4))) float f32x4;

// ws layout (byte offsets, 256-aligned)
#define OFF_COUNT   0u          // int[C]        40960
#define OFF_HEAD    40960u      // int[C]        40960  (init 0xFF = -1)
#define OFF_NEXT    81920u      // int[N]        4096
#define OFF_T3H     86016u      // float[N]      4096
#define OFF_RAUG    90112u      // float[N]      4096
#define OFF_PART    94208u      // float[NT*N*2] 647168
#define OFF_FEATB   741376u     // bf16[N*A]     8388608
#define OFF_A1B     9129984u    // bf16[N*A]     8388608
#define OFF_A2B     17518592u   // bf16[N*A]     8388608
#define WS_BASE     25907200u
#define OFF_WB      25907200u   // bf16[C*A]     81920000
#define OFF_W2B     107827200u  // bf16[C*A]     81920000
#define WS_BIG      189747200u

__device__ inline unsigned short f2bf(float x) {
    union { float f; unsigned u; } v; v.f = x;
    unsigned r = v.u + 0x7FFFu + ((v.u >> 16) & 1u);
    return (unsigned short)(r >> 16);
}

__device__ __forceinline__ void gload16(const void* g, void* l) {
    __builtin_amdgcn_global_load_lds((const __attribute__((address_space(1))) void*)g,
                                     (__attribute__((address_space(3))) void*)l, 16, 0, 0);
}

__global__ void k_wconv(const float* __restrict__ fcw, unsigned short* __restrict__ wb,
                        unsigned short* __restrict__ w2b) {
    const size_t total = (size_t)CC * AA / 4;
    for (size_t i = (size_t)blockIdx.x * 256 + threadIdx.x; i < total; i += (size_t)gridDim.x * 256) {
        float4 v = ((const float4*)fcw)[i];
        ushort4 b, b2;
        b.x = f2bf(v.x); b.y = f2bf(v.y); b.z = f2bf(v.z); b.w = f2bf(v.w);
        b2.x = f2bf(v.x * v.x); b2.y = f2bf(v.y * v.y);
        b2.z = f2bf(v.z * v.z); b2.w = f2bf(v.w * v.w);
        ((ushort4*)wb)[i] = b;
        ((ushort4*)w2b)[i] = b2;
    }
}

// count + per-class linked list (head/next); replaces sumf/sumv atomics.
__global__ void k_count(const int* __restrict__ labels, int* count, int* head, int* nextp) {
    int n = blockIdx.x * 256 + threadIdx.x;
    if (n < NN) {
        int c = labels[n];
        atomicAdd(&count[c], 1);
        nextp[n] = atomicExch(&head[c], n);
    }
}

// Fused per-row prep: class stats via member-list walk -> cv -> bf16 A-operands.
__global__ void k_rowprep(const float* __restrict__ feat, const int* __restrict__ labels,
                          const float* __restrict__ fcw, const float* __restrict__ Ave,
                          const float* __restrict__ CoV, const float* __restrict__ Amount,
                          const int* __restrict__ ratio_p, const int* __restrict__ count,
                          const int* __restrict__ head, const int* __restrict__ nextp,
                          unsigned short* __restrict__ featb, unsigned short* __restrict__ a1b,
                          unsigned short* __restrict__ a2b, float* __restrict__ t3h) {
    int n = blockIdx.x;
    int tid = threadIdx.x;
    int c = labels[n];
    float cnt = (float)count[c];
    float inv = 1.0f / cnt;
    float amt = Amount[c];
    float w = cnt / (cnt + amt);
    float omw = 1.0f - w;
    float w1w = w * omw;
    float rf = (float)(*ratio_p);
    const int h = head[c];
    float t3 = 0.f;
    #pragma unroll 1
    for (int i = 0; i < 4; i++) {
        int i4 = i * 256 + tid;
        float sf[4] = {0.f, 0.f, 0.f, 0.f};
        float sq[4] = {0.f, 0.f, 0.f, 0.f};
        float fvv[4] = {0.f, 0.f, 0.f, 0.f};
        for (int m = h; m >= 0; m = nextp[m]) {
            float4 v = ((const float4*)(feat + (size_t)m * AA))[i4];
            sf[0] += v.x; sf[1] += v.y; sf[2] += v.z; sf[3] += v.w;
            sq[0] += v.x * v.x; sq[1] += v.y * v.y;
            sq[2] += v.z * v.z; sq[3] += v.w * v.w;
            if (m == n) { fvv[0] = v.x; fvv[1] = v.y; fvv[2] = v.z; fvv[3] = v.w; }
        }
        float4 cov = ((const float4*)(CoV + (size_t)c * AA))[i4];
        float4 avv = ((const float4*)(Ave + (size_t)c * AA))[i4];
        float4 wkv = ((const float4*)(fcw + (size_t)c * AA))[i4];
        float cva[4] = {cov.x, cov.y, cov.z, cov.w};
        float ava[4] = {avv.x, avv.y, avv.z, avv.w};
        float wka[4] = {wkv.x, wkv.y, wkv.z, wkv.w};
        ushort4 fb, a1, a2;
        unsigned short ob[12];
        #pragma unroll
        for (int j = 0; j < 4; j++) {
            float ave = sf[j] * inv;
            float var = sq[j] * inv - ave * ave;
            float d = ava[j] - ave;
            float cv = cva[j] * omw + var * w + w1w * d * d;
            float wk = wka[j];
            ob[j]     = f2bf(fvv[j]);
            ob[4 + j] = f2bf(0.5f * rf * cv);
            ob[8 + j] = f2bf(-rf * cv * wk);
            t3 += 0.5f * rf * cv * wk * wk;
        }
        fb.x = ob[0]; fb.y = ob[1]; fb.z = ob[2]; fb.w = ob[3];
        a1.x = ob[4]; a1.y = ob[5]; a1.z = ob[6]; a1.w = ob[7];
        a2.x = ob[8]; a2.y = ob[9]; a2.z = ob[10]; a2.w = ob[11];
        size_t o = (size_t)n * AA + (size_t)i4 * 4;
        *(ushort4*)(featb + o) = fb;
        *(ushort4*)(a1b + o) = a1;
        *(ushort4*)(a2b + o) = a2;
    }
    #pragma unroll
    for (int m = 32; m >= 1; m >>= 1) t3 += __shfl_xor(t3, m, 64);
    __shared__ float red[4];
    if ((tid & 63) == 0) red[tid >> 6] = t3;
    __syncthreads();
    if (tid == 0) t3h[n] = red[0] + red[1] + red[2] + red[3];
}

// ---------- fast GEMM: BK=32 SINGLE-buffer (40KB LDS -> 3-4 blocks/CU) ----
// Occupancy is the lever: all 632 blocks co-resident (no dispatch rounds,
// no tail imbalance), and each block's barrier drain hides under the other
// resident blocks' MFMA (m114 wave-level overlap). Slot-XOR swizzle
// (round-6 proven, 0 conflicts): LDS dest linear, involution on the global
// source slot and on the COMPUTE read address.
__global__ __launch_bounds__(256, 2) void k_gemm(
    const unsigned short* __restrict__ featb, const unsigned short* __restrict__ a1b,
    const unsigned short* __restrict__ a2b, const unsigned short* __restrict__ wbp,
    const unsigned short* __restrict__ w2bp, const float* __restrict__ bias,
    const int* __restrict__ labels, const float* __restrict__ t3h,
    float* __restrict__ yout, float* __restrict__ rowaug, float* __restrict__ part) {
    __shared__ unsigned short sF[4096];
    __shared__ unsigned short sA1[4096];
    __shared__ unsigned short sA2[4096];
    __shared__ unsigned short sW[4096];
    __shared__ unsigned short sW2[4096];

    const int tid = threadIdx.x;
    const int lane = tid & 63;
    const int wid = tid >> 6;
    const int wr = wid >> 1, wc = wid & 1;
    const int lr = lane & 15, lk = lane >> 4;

    // XCD-chunked bijective swizzle: 632 = 8*79; nb-major per XCD.
    const int bid = blockIdx.x;
    const int wg = (bid & 7) * 79 + (bid >> 3);
    const int nb = wg >> 3;
    const int mb = wg & 7;
    const int brow = mb * BM, bcol = nb * BN;

    f32x4 accY[4][4], accS[4][4];
    f32x4 z = {0.f, 0.f, 0.f, 0.f};
    #pragma unroll
    for (int i = 0; i < 4; i++)
        #pragma unroll
        for (int j = 0; j < 4; j++) { accY[i][j] = z; accS[i][j] = z; }

    // staging geometry (BK=32): wave w stages rows [w*32,w*32+32): 2 issues
    // of 16 rows. lane l covers row +(l>>2); global slot = swizzled image of
    // the lane's linear LDS slot (involution per row-pair).
    const int lrow4 = lane >> 2;
    const int scolb = (((lane & 3) ^ ((lane >> 3) & 3)) * 16);
    const size_t R16 = (size_t)16 * AA * 2;
    const char* gF  = (const char*)featb + ((size_t)(brow + wid * 32 + lrow4) * AA) * 2 + scolb;
    const char* gA1 = (const char*)a1b  + ((size_t)(brow + wid * 32 + lrow4) * AA) * 2 + scolb;
    const char* gA2 = (const char*)a2b  + ((size_t)(brow + wid * 32 + lrow4) * AA) * 2 + scolb;
    int cls0 = bcol + wid * 32 + lrow4;      if (cls0 > CC - 1) cls0 = CC - 1;
    int cls1 = bcol + wid * 32 + 16 + lrow4; if (cls1 > CC - 1) cls1 = CC - 1;
    const char* gW0 = (const char*)wbp  + (size_t)cls0 * AA * 2 + scolb;
    const char* gW1 = (const char*)wbp  + (size_t)cls1 * AA * 2 + scolb;
    const char* gV0 = (const char*)w2bp + (size_t)cls0 * AA * 2 + scolb;
    const char* gV1 = (const char*)w2bp + (size_t)cls1 * AA * 2 + scolb;
    const int ldb = wid * 2048;              // byte offset: (wid*32)*64

    #pragma unroll 1
    for (int t = 0; t < 128; t++) {
        const size_t ko = (size_t)t * 64;
        gload16(gF  + ko,       (char*)sF  + ldb);
        gload16(gF  + R16 + ko, (char*)sF  + ldb + 1024);
        gload16(gA1 + ko,       (char*)sA1 + ldb);
        gload16(gA1 + R16 + ko, (char*)sA1 + ldb + 1024);
        gload16(gA2 + ko,       (char*)sA2 + ldb);
        gload16(gA2 + R16 + ko, (char*)sA2 + ldb + 1024);
        gload16(gW0 + ko,       (char*)sW  + ldb);
        gload16(gW1 + ko,       (char*)sW  + ldb + 1024);
        gload16(gV0 + ko,       (char*)sW2 + ldb);
        gload16(gV1 + ko,       (char*)sW2 + ldb + 1024);
        __syncthreads();
        short8 bw_[4], bw2_[4];
        #pragma unroll
        for (int ni = 0; ni < 4; ni++) {
            int row = wc * 64 + ni * 16 + lr;
            int off = row * 64 + ((lk ^ ((row >> 1) & 3)) * 16);
            bw_[ni]  = *(const short8*)((const char*)sW  + off);
            bw2_[ni] = *(const short8*)((const char*)sW2 + off);
        }
        #pragma unroll
        for (int mi = 0; mi < 4; mi++) {
            int row = wr * 64 + mi * 16 + lr;
            int off = row * 64 + ((lk ^ ((row >> 1) & 3)) * 16);
            short8 af  = *(const short8*)((const char*)sF  + off);
            short8 a1f = *(const short8*)((const char*)sA1 + off);
            short8 a2f = *(const short8*)((const char*)sA2 + off);
            #pragma unroll
            for (int ni = 0; ni < 4; ni++) {
                accY[mi][ni] = __builtin_amdgcn_mfma_f32_16x16x32_bf16(af,  bw_[ni],  accY[mi][ni], 0, 0, 0);
                accS[mi][ni] = __builtin_amdgcn_mfma_f32_16x16x32_bf16(a1f, bw2_[ni], accS[mi][ni], 0, 0, 0);
                accS[mi][ni] = __builtin_amdgcn_mfma_f32_16x16x32_bf16(a2f, bw_[ni],  accS[mi][ni], 0, 0, 0);
            }
        }
        __syncthreads();
    }

    // ---- epilogue: y store + online (max,sumexp) partials + label extract ----
    float* sRed = (float*)sF;
    #pragma unroll
    for (int mi = 0; mi < 4; mi++) {
        #pragma unroll
        for (int r = 0; r < 4; r++) {
            int rowt = wr * 64 + mi * 16 + lk * 4 + r;
            int grow = brow + rowt;
            int lab = labels[grow];
            float t3 = t3h[grow];
            float av[4];
            #pragma unroll
            for (int ni = 0; ni < 4; ni++) {
                int gcol = bcol + wc * 64 + ni * 16 + lr;
                float acy = accY[mi][ni][r];
                if (gcol < CC) {
                    float yy = acy + bias[gcol];
                    yout[(size_t)grow * CC + gcol] = yy;
                    float aug = yy + accS[mi][ni][r] + t3;
                    if (gcol == lab) rowaug[grow] = aug;
                    av[ni] = aug;
                } else {
                    av[ni] = -3.0e38f;
                }
            }
            float ml = fmaxf(fmaxf(av[0], av[1]), fmaxf(av[2], av[3]));
            #pragma unroll
            for (int m = 1; m < 16; m <<= 1) ml = fmaxf(ml, __shfl_xor(ml, m, 64));
            float sl = __expf(av[0] - ml) + __expf(av[1] - ml) +
                       __expf(av[2] - ml) + __expf(av[3] - ml);
            #pragma unroll
            for (int m = 1; m < 16; m <<= 1) sl += __shfl_xor(sl, m, 64);
            if (lr == 0) {
                sRed[rowt * 4 + wc * 2 + 0] = ml;
                sRed[rowt * 4 + wc * 2 + 1] = sl;
            }
        }
    }
    __syncthreads();
    if (tid < 128) {
        float m0 = sRed[tid * 4 + 0], s0 = sRed[tid * 4 + 1];
        float m1 = sRed[tid * 4 + 2], s1 = sRed[tid * 4 + 3];
        float M = fmaxf(m0, m1);
        float S = s0 * __expf(m0 - M) + s1 * __expf(m1 - M);
        size_t o = ((size_t)nb * NN + (brow + tid)) * 2;
        part[o] = M;
        part[o + 1] = S;
    }
}

// ---------- fallback GEMM (round-2 proven): in-kernel W conversion ----------
__global__ __launch_bounds__(256, 2) void k_gemm_fb(
    const unsigned short* __restrict__ featb, const unsigned short* __restrict__ a1b,
    const unsigned short* __restrict__ a2b, const float* __restrict__ fcw,
    const float* __restrict__ bias, const int* __restrict__ labels,
    const float* __restrict__ t3h, float* __restrict__ yout,
    float* __restrict__ rowaug, float* __restrict__ part) {
    __shared__ unsigned short sF[BM * 64];
    __shared__ unsigned short sA1[BM * 64];
    __shared__ unsigned short sA2[BM * 64];
    __shared__ unsigned short sW[BN * 64];
    __shared__ unsigned short sW2[BN * 64];

    const int tid = threadIdx.x;
    const int lane = tid & 63;
    const int wid = tid >> 6;
    const int wr = wid >> 1, wc = wid & 1;
    const int lr = lane & 15, lk = lane >> 4;
    const int nb = blockIdx.x, mb = blockIdx.y;
    const int brow = mb * BM, bcol = nb * BN;

    f32x4 accY[4][4], accS[4][4];
    f32x4 z = {0.f, 0.f, 0.f, 0.f};
    #pragma unroll
    for (int i = 0; i < 4; i++)
        #pragma unroll
        for (int j = 0; j < 4; j++) { accY[i][j] = z; accS[i][j] = z; }

    const int srow = tid >> 3;
    const int sblk = tid & 7;

    for (int kt = 0; kt < AA; kt += 64) {
        #pragma unroll
        for (int p = 0; p < 4; p++) {
            int row = p * 32 + srow;
            size_t g = (size_t)(brow + row) * AA + kt + sblk * 8;
            int pos = row * 128 + ((sblk * 16) ^ ((row & 7) << 4));
            *(uint4*)((char*)sF + pos)  = *(const uint4*)(featb + g);
            *(uint4*)((char*)sA1 + pos) = *(const uint4*)(a1b + g);
            *(uint4*)((char*)sA2 + pos) = *(const uint4*)(a2b + g);
        }
        #pragma unroll
        for (int p = 0; p < 8; p++) {
            int idx = p * 256 + tid;
            int wrow = idx >> 4;
            int col4 = idx & 15;
            int cls = bcol + wrow;
            float4 wv = {0.f, 0.f, 0.f, 0.f};
            if (cls < CC) wv = *(const float4*)(fcw + (size_t)cls * AA + kt + col4 * 4);
            ushort4 wb, w2b;
            wb.x = f2bf(wv.x); wb.y = f2bf(wv.y); wb.z = f2bf(wv.z); wb.w = f2bf(wv.w);
            w2b.x = f2bf(wv.x * wv.x); w2b.y = f2bf(wv.y * wv.y);
            w2b.z = f2bf(wv.z * wv.z); w2b.w = f2bf(wv.w * wv.w);
            int pos = wrow * 128 + ((col4 * 8) ^ ((wrow & 7) << 4));
            *(ushort4*)((char*)sW + pos) = wb;
            *(ushort4*)((char*)sW2 + pos) = w2b;
        }
        __syncthreads();
        #pragma unroll
        for (int k2 = 0; k2 < 2; k2++) {
            int kb = k2 * 64 + lk * 16;
            short8 bw[4], bw2[4];
            #pragma unroll
            for (int ni = 0; ni < 4; ni++) {
                int row = wc * 64 + ni * 16 + lr;
                int off = row * 128 + (kb ^ ((row & 7) << 4));
                bw[ni]  = *(const short8*)((const char*)sW + off);
                bw2[ni] = *(const short8*)((const char*)sW2 + off);
            }
            #pragma unroll
            for (int mi = 0; mi < 4; mi++) {
                int row = wr * 64 + mi * 16 + lr;
                int off = row * 128 + (kb ^ ((row & 7) << 4));
                short8 af  = *(const short8*)((const char*)sF + off);
                short8 a1f = *(const short8*)((const char*)sA1 + off);
                short8 a2f = *(const short8*)((const char*)sA2 + off);
                #pragma unroll
                for (int ni = 0; ni < 4; ni++) {
                    accY[mi][ni] = __builtin_amdgcn_mfma_f32_16x16x32_bf16(af,  bw[ni],  accY[mi][ni], 0, 0, 0);
                    accS[mi][ni] = __builtin_amdgcn_mfma_f32_16x16x32_bf16(a1f, bw2[ni], accS[mi][ni], 0, 0, 0);
                    accS[mi][ni] = __builtin_amdgcn_mfma_f32_16x16x32_bf16(a2f, bw[ni],  accS[mi][ni], 0, 0, 0);
                }
            }
        }
        __syncthreads();
    }

    float* sRed = (float*)sF;
    #pragma unroll
    for (int mi = 0; mi < 4; mi++) {
        #pragma unroll
        for (int r = 0; r < 4; r++) {
            int rowt = wr * 64 + mi * 16 + lk * 4 + r;
            int grow = brow + rowt;
            int lab = labels[grow];
            float t3 = t3h[grow];
            float av[4];
            #pragma unroll
            for (int ni = 0; ni < 4; ni++) {
                int gcol = bcol + wc * 64 + ni * 16 + lr;
                float acy = accY[mi][ni][r];
                if (gcol < CC) {
                    float yy = acy + bias[gcol];
                    yout[(size_t)grow * CC + gcol] = yy;
                    float aug = yy + accS[mi][ni][r] + t3;
                    if (gcol == lab) rowaug[grow] = aug;
                    av[ni] = aug;
                } else {
                    av[ni] = -3.0e38f;
                }
            }
            float ml = fmaxf(fmaxf(av[0], av[1]), fmaxf(av[2], av[3]));
            #pragma unroll
            for (int m = 1; m < 16; m <<= 1) ml = fmaxf(ml, __shfl_xor(ml, m, 64));
            float sl = __expf(av[0] - ml) + __expf(av[1] - ml) +
                       __expf(av[2] - ml) + __expf(av[3] - ml);
            #pragma unroll
            for (int m = 1; m < 16; m <<= 1) sl += __shfl_xor(sl, m, 64);
            if (lr == 0) {
                sRed[rowt * 4 + wc * 2 + 0] = ml;
                sRed[rowt * 4 + wc * 2 + 1] = sl;
            }
        }
    }
    __syncthreads();
    if (tid < 128) {
        float m0 = sRed[tid * 4 + 0], s0 = sRed[tid * 4 + 1];
        float m1 = sRed[tid * 4 + 2], s1 = sRed[tid * 4 + 3];
        float M = fmaxf(m0, m1);
        float S = s0 * __expf(m0 - M) + s1 * __expf(m1 - M);
        size_t o = ((size_t)nb * NN + (brow + tid)) * 2;
        part[o] = M;
        part[o + 1] = S;
    }
}

__global__ void k_loss(const float* __restrict__ part, const float* __restrict__ rowaug,
                       float* __restrict__ out0) {
    __shared__ float red[256];
    int n = blockIdx.x * 256 + threadIdx.x;
    float M = -3.0e38f;
    for (int t = 0; t < NT; t++) M = fmaxf(M, part[((size_t)t * NN + n) * 2]);
    float S = 0.f;
    for (int t = 0; t < NT; t++) {
        float m = part[((size_t)t * NN + n) * 2];
        float s = part[((size_t)t * NN + n) * 2 + 1];
        S += s * __expf(m - M);
    }
    float lse = M + logf(S);
    float rl = lse - rowaug[n];
    red[threadIdx.x] = rl;
    __syncthreads();
    for (int st = 128; st > 0; st >>= 1) {
        if (threadIdx.x < st) red[threadIdx.x] += red[threadIdx.x + st];
        __syncthreads();
    }
    if (threadIdx.x == 0) atomicAdd(out0, red[0] * (1.0f / (float)NN));
}

extern "C" void kernel_launch(void* const* d_in, const int* in_sizes, int n_in,
                              void* d_out, int out_size, void* d_ws, size_t ws_size,
                              hipStream_t stream) {
    const float* feat   = (const float*)d_in[0];
    const int*   labels = (const int*)d_in[1];
    const float* fcw    = (const float*)d_in[2];
    const float* bias   = (const float*)d_in[3];
    const float* Ave    = (const float*)d_in[4];
    const float* CoV    = (const float*)d_in[5];
    const float* Amount = (const float*)d_in[6];
    const int*   ratio  = (const int*)d_in[7];

    if (ws_size < WS_BASE) return;
    const bool big = ws_size >= WS_BIG;

    char* w = (char*)d_ws;
    int*   count  = (int*)(w + OFF_COUNT);
    int*   head   = (int*)(w + OFF_HEAD);
    int*   nextp  = (int*)(w + OFF_NEXT);
    float* t3h    = (float*)(w + OFF_T3H);
    float* rowaug = (float*)(w + OFF_RAUG);
    float* part   = (float*)(w + OFF_PART);
    unsigned short* featb = (unsigned short*)(w + OFF_FEATB);
    unsigned short* a1b   = (unsigned short*)(w + OFF_A1B);
    unsigned short* a2b   = (unsigned short*)(w + OFF_A2B);
    unsigned short* wb    = (unsigned short*)(w + OFF_WB);
    unsigned short* w2b   = (unsigned short*)(w + OFF_W2B);

    float* out = (float*)d_out;
    float* yout = out + 1;

    hipMemsetAsync(w + OFF_COUNT, 0, 40960, stream);
    hipMemsetAsync(w + OFF_HEAD, 0xFF, 40960, stream);   // head[c] = -1
    hipMemsetAsync(d_out, 0, 4, stream);                  // loss accumulator

    if (big) k_wconv<<<dim3(2048), dim3(256), 0, stream>>>(fcw, wb, w2b);
    k_count<<<dim3(4), dim3(256), 0, stream>>>(labels, count, head, nextp);
    k_rowprep<<<dim3(NN), dim3(256), 0, stream>>>(feat, labels, fcw, Ave, CoV, Amount,
                                                  ratio, count, head, nextp,
                                                  featb, a1b, a2b, t3h);
    if (big) {
        k_gemm<<<dim3(NT * 8), dim3(256), 0, stream>>>(featb, a1b, a2b, wb, w2b, bias,
                                                       labels, t3h, yout, rowaug, part);
    } else {
        k_gemm_fb<<<dim3(NT, 8), dim3(256), 0, stream>>>(featb, a1b, a2b, fcw, bias, labels,
                                                         t3h, yout, rowaug, part);
    }
    k_loss<<<dim3(4), dim3(256), 0, stream>>>(part, rowaug, out);
}

// Round 10
// 356.381 us; speedup vs baseline: 1.4251x; 1.4058x over previous
//
#include <hip/hip_runtime.h>
#include <hip/hip_bf16.h>
#include <math.h>

#define NN 1024
#define AA 4096
#define CC 10000
#define NT 79
#define BM 64
#define BN 128

typedef __attribute__((ext_vector_type(8))) short short8;
typedef __attribute__((ext_vector_type(4))) float f32x4;

// ws layout (byte offsets, 256-aligned)
#define OFF_COUNT   0u          // int[C]        40960
#define OFF_HEAD    40960u      // int[C]        40960  (init 0xFF = -1)
#define OFF_NEXT    81920u      // int[N]        4096
#define OFF_T3H     86016u      // float[N]      4096
#define OFF_RAUG    90112u      // float[N]      4096
#define OFF_PART    94208u      // float[NT*N*2] 647168
#define OFF_FEATB   741376u     // bf16[N*A]     8388608
#define OFF_A1B     9129984u    // bf16[N*A]     8388608
#define OFF_A2B     17518592u   // bf16[N*A]     8388608
#define WS_BASE     25907200u
#define OFF_WB      25907200u   // bf16[C*A]     81920000
#define WS_BIG      107827200u

__device__ inline unsigned short f2bf(float x) {
    union { float f; unsigned u; } v; v.f = x;
    unsigned r = v.u + 0x7FFFu + ((v.u >> 16) & 1u);
    return (unsigned short)(r >> 16);
}

__device__ __forceinline__ void gload16(const void* g, void* l) {
    __builtin_amdgcn_global_load_lds((const __attribute__((address_space(1))) void*)g,
                                     (__attribute__((address_space(3))) void*)l, 16, 0, 0);
}

// elementwise square of a bf16x8 fragment, in registers (RNE via cvt_pk).
__device__ __forceinline__ short8 bfsq(short8 w) {
    union U { short8 s; unsigned u[4]; } in, out;
    in.s = w;
    #pragma unroll
    for (int i = 0; i < 4; i++) {
        unsigned u = in.u[i];
        float lo = __uint_as_float(u << 16);
        float hi = __uint_as_float(u & 0xffff0000u);
        float sl = lo * lo;
        float sh = hi * hi;
        unsigned p;
        asm("v_cvt_pk_bf16_f32 %0, %1, %2" : "=v"(p) : "v"(sl), "v"(sh));
        out.u[i] = p;
    }
    return out.s;
}

__global__ void k_wconv(const float* __restrict__ fcw, unsigned short* __restrict__ wb) {
    const size_t total = (size_t)CC * AA / 4;
    for (size_t i = (size_t)blockIdx.x * 256 + threadIdx.x; i < total; i += (size_t)gridDim.x * 256) {
        float4 v = ((const float4*)fcw)[i];
        ushort4 b;
        b.x = f2bf(v.x); b.y = f2bf(v.y); b.z = f2bf(v.z); b.w = f2bf(v.w);
        ((ushort4*)wb)[i] = b;
    }
}

// count + per-class linked list (head/next).
__global__ void k_count(const int* __restrict__ labels, int* count, int* head, int* nextp) {
    int n = blockIdx.x * 256 + threadIdx.x;
    if (n < NN) {
        int c = labels[n];
        atomicAdd(&count[c], 1);
        nextp[n] = atomicExch(&head[c], n);
    }
}

// Fused per-row prep: class stats via member-list walk -> cv -> bf16 A-operands.
__global__ void k_rowprep(const float* __restrict__ feat, const int* __restrict__ labels,
                          const float* __restrict__ fcw, const float* __restrict__ Ave,
                          const float* __restrict__ CoV, const float* __restrict__ Amount,
                          const int* __restrict__ ratio_p, const int* __restrict__ count,
                          const int* __restrict__ head, const int* __restrict__ nextp,
                          unsigned short* __restrict__ featb, unsigned short* __restrict__ a1b,
                          unsigned short* __restrict__ a2b, float* __restrict__ t3h) {
    int n = blockIdx.x;
    int tid = threadIdx.x;
    int c = labels[n];
    float cnt = (float)count[c];
    float inv = 1.0f / cnt;
    float amt = Amount[c];
    float w = cnt / (cnt + amt);
    float omw = 1.0f - w;
    float w1w = w * omw;
    float rf = (float)(*ratio_p);
    const int h = head[c];
    float t3 = 0.f;
    #pragma unroll 1
    for (int i = 0; i < 4; i++) {
        int i4 = i * 256 + tid;
        float sf[4] = {0.f, 0.f, 0.f, 0.f};
        float sq[4] = {0.f, 0.f, 0.f, 0.f};
        float fvv[4] = {0.f, 0.f, 0.f, 0.f};
        for (int m = h; m >= 0; m = nextp[m]) {
            float4 v = ((const float4*)(feat + (size_t)m * AA))[i4];
            sf[0] += v.x; sf[1] += v.y; sf[2] += v.z; sf[3] += v.w;
            sq[0] += v.x * v.x; sq[1] += v.y * v.y;
            sq[2] += v.z * v.z; sq[3] += v.w * v.w;
            if (m == n) { fvv[0] = v.x; fvv[1] = v.y; fvv[2] = v.z; fvv[3] = v.w; }
        }
        float4 cov = ((const float4*)(CoV + (size_t)c * AA))[i4];
        float4 avv = ((const float4*)(Ave + (size_t)c * AA))[i4];
        float4 wkv = ((const float4*)(fcw + (size_t)c * AA))[i4];
        float cva[4] = {cov.x, cov.y, cov.z, cov.w};
        float ava[4] = {avv.x, avv.y, avv.z, avv.w};
        float wka[4] = {wkv.x, wkv.y, wkv.z, wkv.w};
        ushort4 fb, a1, a2;
        unsigned short ob[12];
        #pragma unroll
        for (int j = 0; j < 4; j++) {
            float ave = sf[j] * inv;
            float var = sq[j] * inv - ave * ave;
            float d = ava[j] - ave;
            float cv = cva[j] * omw + var * w + w1w * d * d;
            float wk = wka[j];
            ob[j]     = f2bf(fvv[j]);
            ob[4 + j] = f2bf(0.5f * rf * cv);
            ob[8 + j] = f2bf(-rf * cv * wk);
            t3 += 0.5f * rf * cv * wk * wk;
        }
        fb.x = ob[0]; fb.y = ob[1]; fb.z = ob[2]; fb.w = ob[3];
        a1.x = ob[4]; a1.y = ob[5]; a1.z = ob[6]; a1.w = ob[7];
        a2.x = ob[8]; a2.y = ob[9]; a2.z = ob[10]; a2.w = ob[11];
        size_t o = (size_t)n * AA + (size_t)i4 * 4;
        *(ushort4*)(featb + o) = fb;
        *(ushort4*)(a1b + o) = a1;
        *(ushort4*)(a2b + o) = a2;
    }
    #pragma unroll
    for (int m = 32; m >= 1; m >>= 1) t3 += __shfl_xor(t3, m, 64);
    __shared__ float red[4];
    if ((tid & 63) == 0) red[tid >> 6] = t3;
    __syncthreads();
    if (tid == 0) t3h[n] = red[0] + red[1] + red[2] + red[3];
}

// ---------- fast GEMM: BM=64 x BN=128, wave=32x64, acc=64 regs, BK=64,
// single-buffer 40KB LDS, W^2 computed in registers (no W2 stream).
// Goal: per-wave regs ~150 -> 3-4 waves/SIMD residency (TLP hides the
// per-K-step latency chain). Proven 8-row XOR involution (0 conflicts):
// LDS dest linear, involution on global source col and on read address.
__global__ __launch_bounds__(256, 2) void k_gemm(
    const unsigned short* __restrict__ featb, const unsigned short* __restrict__ a1b,
    const unsigned short* __restrict__ a2b, const unsigned short* __restrict__ wbp,
    const float* __restrict__ bias, const int* __restrict__ labels,
    const float* __restrict__ t3h, float* __restrict__ yout,
    float* __restrict__ rowaug, float* __restrict__ part) {
    __shared__ unsigned short sF[BM * 64];    // 8KB
    __shared__ unsigned short sA1[BM * 64];   // 8KB
    __shared__ unsigned short sA2[BM * 64];   // 8KB
    __shared__ unsigned short sW[BN * 64];    // 16KB

    const int tid = threadIdx.x;
    const int lane = tid & 63;
    const int wid = tid >> 6;
    const int wr = wid >> 1, wc = wid & 1;    // wave = rows wr*32.., cols wc*64..
    const int lr = lane & 15, lk = lane >> 4;

    // XCD-chunked bijective swizzle: 1264 = 8*158; nb-major per XCD.
    const int bid = blockIdx.x;
    const int wg = (bid & 7) * 158 + (bid >> 3);
    const int nb = wg >> 4;
    const int mb = wg & 15;
    const int brow = mb * BM, bcol = nb * BN;

    f32x4 accY[2][4], accS[2][4];
    f32x4 z = {0.f, 0.f, 0.f, 0.f};
    #pragma unroll
    for (int i = 0; i < 2; i++)
        #pragma unroll
        for (int j = 0; j < 4; j++) { accY[i][j] = z; accS[i][j] = z; }

    // staging: A-streams: wave stages rows [w*16, w*16+16) (2 chunks of 8);
    // W: rows [w*32, w*32+32) (4 chunks). lane covers row chunk+ (l>>3),
    // 16B at swizzled col cb (8-row involution; row&7 == l>>3 per chunk).
    const int lrow8 = lane >> 3;
    const int cb = ((lane & 7) * 16) ^ (lrow8 << 4);
    const size_t rowstep = (size_t)8 * AA * 2;
    const size_t abase = ((size_t)(brow + wid * 16 + lrow8) * AA) * 2 + cb;
    const char* gF  = (const char*)featb + abase;
    const char* gA1 = (const char*)a1b + abase;
    const char* gA2 = (const char*)a2b + abase;
    size_t woff[4];
    #pragma unroll
    for (int q = 0; q < 4; q++) {
        int cls = bcol + wid * 32 + q * 8 + lrow8;
        if (cls > CC - 1) cls = CC - 1;
        woff[q] = (size_t)cls * AA * 2 + cb;
    }
    const int ldbA = wid * 2048;   // (wid*16 rows)*128B
    const int ldbW = wid * 4096;   // (wid*32 rows)*128B

    for (int kt = 0; kt < AA; kt += 64) {
        const size_t ko = (size_t)kt * 2;
        #pragma unroll
        for (int q = 0; q < 2; q++) {
            const size_t ao = (size_t)q * rowstep + ko;
            const int ld = ldbA + q * 1024;
            gload16(gF + ao, (char*)sF + ld);
            gload16(gA1 + ao, (char*)sA1 + ld);
            gload16(gA2 + ao, (char*)sA2 + ld);
        }
        #pragma unroll
        for (int q = 0; q < 4; q++) {
            gload16((const char*)wbp + woff[q] + ko, (char*)sW + ldbW + q * 1024);
        }
        __syncthreads();
        #pragma unroll
        for (int k2 = 0; k2 < 2; k2++) {
            int kb = k2 * 64 + lk * 16;
            short8 bw[4], bw2[4];
            #pragma unroll
            for (int ni = 0; ni < 4; ni++) {
                int row = wc * 64 + ni * 16 + lr;
                int off = row * 128 + (kb ^ ((row & 7) << 4));
                bw[ni] = *(const short8*)((const char*)sW + off);
                bw2[ni] = bfsq(bw[ni]);
            }
            #pragma unroll
            for (int mi = 0; mi < 2; mi++) {
                int row = wr * 32 + mi * 16 + lr;
                int off = row * 128 + (kb ^ ((row & 7) << 4));
                short8 af  = *(const short8*)((const char*)sF + off);
                short8 a1f = *(const short8*)((const char*)sA1 + off);
                short8 a2f = *(const short8*)((const char*)sA2 + off);
                #pragma unroll
                for (int ni = 0; ni < 4; ni++) {
                    accY[mi][ni] = __builtin_amdgcn_mfma_f32_16x16x32_bf16(af,  bw[ni],  accY[mi][ni], 0, 0, 0);
                    accS[mi][ni] = __builtin_amdgcn_mfma_f32_16x16x32_bf16(a1f, bw2[ni], accS[mi][ni], 0, 0, 0);
                    accS[mi][ni] = __builtin_amdgcn_mfma_f32_16x16x32_bf16(a2f, bw[ni],  accS[mi][ni], 0, 0, 0);
                }
            }
        }
        __syncthreads();
    }

    // ---- epilogue: y store + online (max,sumexp) partials + label extract ----
    float* sRed = (float*)sF;  // needs 64*4 = 256 floats
    #pragma unroll
    for (int mi = 0; mi < 2; mi++) {
        #pragma unroll
        for (int r = 0; r < 4; r++) {
            int rowt = wr * 32 + mi * 16 + lk * 4 + r;
            int grow = brow + rowt;
            int lab = labels[grow];
            float t3 = t3h[grow];
            float av[4];
            #pragma unroll
            for (int ni = 0; ni < 4; ni++) {
                int gcol = bcol + wc * 64 + ni * 16 + lr;
                float acy = accY[mi][ni][r];
                if (gcol < CC) {
                    float yy = acy + bias[gcol];
                    yout[(size_t)grow * CC + gcol] = yy;
                    float aug = yy + accS[mi][ni][r] + t3;
                    if (gcol == lab) rowaug[grow] = aug;
                    av[ni] = aug;
                } else {
                    av[ni] = -3.0e38f;
                }
            }
            float ml = fmaxf(fmaxf(av[0], av[1]), fmaxf(av[2], av[3]));
            #pragma unroll
            for (int m = 1; m < 16; m <<= 1) ml = fmaxf(ml, __shfl_xor(ml, m, 64));
            float sl = __expf(av[0] - ml) + __expf(av[1] - ml) +
                       __expf(av[2] - ml) + __expf(av[3] - ml);
            #pragma unroll
            for (int m = 1; m < 16; m <<= 1) sl += __shfl_xor(sl, m, 64);
            if (lr == 0) {
                sRed[rowt * 4 + wc * 2 + 0] = ml;
                sRed[rowt * 4 + wc * 2 + 1] = sl;
            }
        }
    }
    __syncthreads();
    if (tid < 64) {
        float m0 = sRed[tid * 4 + 0], s0 = sRed[tid * 4 + 1];
        float m1 = sRed[tid * 4 + 2], s1 = sRed[tid * 4 + 3];
        float M = fmaxf(m0, m1);
        float S = s0 * __expf(m0 - M) + s1 * __expf(m1 - M);
        size_t o = ((size_t)nb * NN + (brow + tid)) * 2;
        part[o] = M;
        part[o + 1] = S;
    }
}

// ---------- fallback GEMM (round-2 proven): in-kernel W conversion ----------
__global__ __launch_bounds__(256, 2) void k_gemm_fb(
    const unsigned short* __restrict__ featb, const unsigned short* __restrict__ a1b,
    const unsigned short* __restrict__ a2b, const float* __restrict__ fcw,
    const float* __restrict__ bias, const int* __restrict__ labels,
    const float* __restrict__ t3h, float* __restrict__ yout,
    float* __restrict__ rowaug, float* __restrict__ part) {
    __shared__ unsigned short sF[128 * 64];
    __shared__ unsigned short sA1[128 * 64];
    __shared__ unsigned short sA2[128 * 64];
    __shared__ unsigned short sW[128 * 64];
    __shared__ unsigned short sW2[128 * 64];

    const int tid = threadIdx.x;
    const int lane = tid & 63;
    const int wid = tid >> 6;
    const int wr = wid >> 1, wc = wid & 1;
    const int lr = lane & 15, lk = lane >> 4;
    const int nb = blockIdx.x, mb = blockIdx.y;
    const int brow = mb * 128, bcol = nb * 128;

    f32x4 accY[4][4], accS[4][4];
    f32x4 z = {0.f, 0.f, 0.f, 0.f};
    #pragma unroll
    for (int i = 0; i < 4; i++)
        #pragma unroll
        for (int j = 0; j < 4; j++) { accY[i][j] = z; accS[i][j] = z; }

    const int srow = tid >> 3;
    const int sblk = tid & 7;

    for (int kt = 0; kt < AA; kt += 64) {
        #pragma unroll
        for (int p = 0; p < 4; p++) {
            int row = p * 32 + srow;
            size_t g = (size_t)(brow + row) * AA + kt + sblk * 8;
            int pos = row * 128 + ((sblk * 16) ^ ((row & 7) << 4));
            *(uint4*)((char*)sF + pos)  = *(const uint4*)(featb + g);
            *(uint4*)((char*)sA1 + pos) = *(const uint4*)(a1b + g);
            *(uint4*)((char*)sA2 + pos) = *(const uint4*)(a2b + g);
        }
        #pragma unroll
        for (int p = 0; p < 8; p++) {
            int idx = p * 256 + tid;
            int wrow = idx >> 4;
            int col4 = idx & 15;
            int cls = bcol + wrow;
            float4 wv = {0.f, 0.f, 0.f, 0.f};
            if (cls < CC) wv = *(const float4*)(fcw + (size_t)cls * AA + kt + col4 * 4);
            ushort4 wb, w2b;
            wb.x = f2bf(wv.x); wb.y = f2bf(wv.y); wb.z = f2bf(wv.z); wb.w = f2bf(wv.w);
            w2b.x = f2bf(wv.x * wv.x); w2b.y = f2bf(wv.y * wv.y);
            w2b.z = f2bf(wv.z * wv.z); w2b.w = f2bf(wv.w * wv.w);
            int pos = wrow * 128 + ((col4 * 8) ^ ((wrow & 7) << 4));
            *(ushort4*)((char*)sW + pos) = wb;
            *(ushort4*)((char*)sW2 + pos) = w2b;
        }
        __syncthreads();
        #pragma unroll
        for (int k2 = 0; k2 < 2; k2++) {
            int kb = k2 * 64 + lk * 16;
            short8 bw[4], bw2[4];
            #pragma unroll
            for (int ni = 0; ni < 4; ni++) {
                int row = wc * 64 + ni * 16 + lr;
                int off = row * 128 + (kb ^ ((row & 7) << 4));
                bw[ni]  = *(const short8*)((const char*)sW + off);
                bw2[ni] = *(const short8*)((const char*)sW2 + off);
            }
            #pragma unroll
            for (int mi = 0; mi < 4; mi++) {
                int row = wr * 64 + mi * 16 + lr;
                int off = row * 128 + (kb ^ ((row & 7) << 4));
                short8 af  = *(const short8*)((const char*)sF + off);
                short8 a1f = *(const short8*)((const char*)sA1 + off);
                short8 a2f = *(const short8*)((const char*)sA2 + off);
                #pragma unroll
                for (int ni = 0; ni < 4; ni++) {
                    accY[mi][ni] = __builtin_amdgcn_mfma_f32_16x16x32_bf16(af,  bw[ni],  accY[mi][ni], 0, 0, 0);
                    accS[mi][ni] = __builtin_amdgcn_mfma_f32_16x16x32_bf16(a1f, bw2[ni], accS[mi][ni], 0, 0, 0);
                    accS[mi][ni] = __builtin_amdgcn_mfma_f32_16x16x32_bf16(a2f, bw[ni],  accS[mi][ni], 0, 0, 0);
                }
            }
        }
        __syncthreads();
    }

    float* sRed = (float*)sF;
    #pragma unroll
    for (int mi = 0; mi < 4; mi++) {
        #pragma unroll
        for (int r = 0; r < 4; r++) {
            int rowt = wr * 64 + mi * 16 + lk * 4 + r;
            int grow = brow + rowt;
            int lab = labels[grow];
            float t3 = t3h[grow];
            float av[4];
            #pragma unroll
            for (int ni = 0; ni < 4; ni++) {
                int gcol = bcol + wc * 64 + ni * 16 + lr;
                float acy = accY[mi][ni][r];
                if (gcol < CC) {
                    float yy = acy + bias[gcol];
                    yout[(size_t)grow * CC + gcol] = yy;
                    float aug = yy + accS[mi][ni][r] + t3;
                    if (gcol == lab) rowaug[grow] = aug;
                    av[ni] = aug;
                } else {
                    av[ni] = -3.0e38f;
                }
            }
            float ml = fmaxf(fmaxf(av[0], av[1]), fmaxf(av[2], av[3]));
            #pragma unroll
            for (int m = 1; m < 16; m <<= 1) ml = fmaxf(ml, __shfl_xor(ml, m, 64));
            float sl = __expf(av[0] - ml) + __expf(av[1] - ml) +
                       __expf(av[2] - ml) + __expf(av[3] - ml);
            #pragma unroll
            for (int m = 1; m < 16; m <<= 1) sl += __shfl_xor(sl, m, 64);
            if (lr == 0) {
                sRed[rowt * 4 + wc * 2 + 0] = ml;
                sRed[rowt * 4 + wc * 2 + 1] = sl;
            }
        }
    }
    __syncthreads();
    if (tid < 128) {
        float m0 = sRed[tid * 4 + 0], s0 = sRed[tid * 4 + 1];
        float m1 = sRed[tid * 4 + 2], s1 = sRed[tid * 4 + 3];
        float M = fmaxf(m0, m1);
        float S = s0 * __expf(m0 - M) + s1 * __expf(m1 - M);
        size_t o = ((size_t)nb * NN + (brow + tid)) * 2;
        part[o] = M;
        part[o + 1] = S;
    }
}

__global__ void k_loss(const float* __restrict__ part, const float* __restrict__ rowaug,
                       float* __restrict__ out0) {
    __shared__ float red[256];
    int n = blockIdx.x * 256 + threadIdx.x;
    float M = -3.0e38f;
    for (int t = 0; t < NT; t++) M = fmaxf(M, part[((size_t)t * NN + n) * 2]);
    float S = 0.f;
    for (int t = 0; t < NT; t++) {
        float m = part[((size_t)t * NN + n) * 2];
        float s = part[((size_t)t * NN + n) * 2 + 1];
        S += s * __expf(m - M);
    }
    float lse = M + logf(S);
    float rl = lse - rowaug[n];
    red[threadIdx.x] = rl;
    __syncthreads();
    for (int st = 128; st > 0; st >>= 1) {
        if (threadIdx.x < st) red[threadIdx.x] += red[threadIdx.x + st];
        __syncthreads();
    }
    if (threadIdx.x == 0) atomicAdd(out0, red[0] * (1.0f / (float)NN));
}

extern "C" void kernel_launch(void* const* d_in, const int* in_sizes, int n_in,
                              void* d_out, int out_size, void* d_ws, size_t ws_size,
                              hipStream_t stream) {
    const float* feat   = (const float*)d_in[0];
    const int*   labels = (const int*)d_in[1];
    const float* fcw    = (const float*)d_in[2];
    const float* bias   = (const float*)d_in[3];
    const float* Ave    = (const float*)d_in[4];
    const float* CoV    = (const float*)d_in[5];
    const float* Amount = (const float*)d_in[6];
    const int*   ratio  = (const int*)d_in[7];

    if (ws_size < WS_BASE) return;
    const bool big = ws_size >= WS_BIG;

    char* w = (char*)d_ws;
    int*   count  = (int*)(w + OFF_COUNT);
    int*   head   = (int*)(w + OFF_HEAD);
    int*   nextp  = (int*)(w + OFF_NEXT);
    float* t3h    = (float*)(w + OFF_T3H);
    float* rowaug = (float*)(w + OFF_RAUG);
    float* part   = (float*)(w + OFF_PART);
    unsigned short* featb = (unsigned short*)(w + OFF_FEATB);
    unsigned short* a1b   = (unsigned short*)(w + OFF_A1B);
    unsigned short* a2b   = (unsigned short*)(w + OFF_A2B);
    unsigned short* wb    = (unsigned short*)(w + OFF_WB);

    float* out = (float*)d_out;
    float* yout = out + 1;

    hipMemsetAsync(w + OFF_COUNT, 0, 40960, stream);
    hipMemsetAsync(w + OFF_HEAD, 0xFF, 40960, stream);   // head[c] = -1
    hipMemsetAsync(d_out, 0, 4, stream);                  // loss accumulator

    if (big) k_wconv<<<dim3(2048), dim3(256), 0, stream>>>(fcw, wb);
    k_count<<<dim3(4), dim3(256), 0, stream>>>(labels, count, head, nextp);
    k_rowprep<<<dim3(NN), dim3(256), 0, stream>>>(feat, labels, fcw, Ave, CoV, Amount,
                                                  ratio, count, head, nextp,
                                                  featb, a1b, a2b, t3h);
    if (big) {
        k_gemm<<<dim3(16 * NT), dim3(256), 0, stream>>>(featb, a1b, a2b, wb, bias,
                                                        labels, t3h, yout, rowaug, part);
    } else {
        k_gemm_fb<<<dim3(NT, 8), dim3(256), 0, stream>>>(featb, a1b, a2b, fcw, bias, labels,
                                                         t3h, yout, rowaug, part);
    }
    k_loss<<<dim3(4), dim3(256), 0, stream>>>(part, rowaug, out);
}